// Round 14
// baseline (400.753 us; speedup 1.0000x reference)
//
#include <hip/hip_runtime.h>

#define NROWS 2048      // S*N rows
#define NN    1024
#define DIMM  768
#define HEADS 16
#define CH    48
#define CPAIR 128

typedef unsigned short u16;
typedef unsigned int   u32;
typedef __attribute__((ext_vector_type(8))) short short8;
typedef __attribute__((ext_vector_type(4))) float f32x4;

__device__ __forceinline__ float sigm(float x){ return 1.0f/(1.0f+__expf(-x)); }
__device__ __forceinline__ u16 f2bf(float x){
    u32 u = __float_as_uint(x);
    u32 r = u + 0x7FFFu + ((u>>16)&1u);
    return (u16)(r>>16);
}
__device__ __forceinline__ float bf2f(u16 h){ return __uint_as_float(((u32)h)<<16); }
__device__ __forceinline__ void bfsplit(float x, u16& hi, u16& lo){
    hi = f2bf(x);
    lo = f2bf(x - bf2f(hi));
}
__device__ __forceinline__ short8 zero8(){ short8 z = {0,0,0,0,0,0,0,0}; return z; }

// ---------------------------------------------------------------------------
// K1: fused {ln_single (blocks 0..2047), wsplit (2048..3199), pair_pre (3200)}
// ---------------------------------------------------------------------------
__global__ __launch_bounds__(256) void k_pre(
    const float* __restrict__ srep, const float* __restrict__ sproj,
    const float* __restrict__ sw, float* __restrict__ a_ln,
    u16* __restrict__ shi, u16* __restrict__ slo,
    const float* __restrict__ w0, const float* __restrict__ w1,
    const float* __restrict__ w2, const float* __restrict__ w3,
    const float* __restrict__ w4, const float* __restrict__ w5,
    const float* __restrict__ w6, const float* __restrict__ w7,
    u16* __restrict__ wt,
    const float* __restrict__ plnw, const float* __restrict__ plnb,
    const float* __restrict__ wp, float* __restrict__ wpc,
    float* __restrict__ csb)
{
    __shared__ float tile[64][68];
    __shared__ float red[16];
    int bid = blockIdx.x, t = threadIdx.x;
    if (bid < 2048){
        int r = bid;
        const float* xa = srep  + (size_t)r*DIMM;
        const float* xs = sproj + (size_t)r*DIMM;
        float va[3], vs[3];
        float sa=0.f,qa=0.f,ss=0.f,qs=0.f;
        #pragma unroll
        for (int i=0;i<3;i++){ float x=xa[t+256*i]; va[i]=x; sa+=x; qa+=x*x; }
        #pragma unroll
        for (int i=0;i<3;i++){ float x=xs[t+256*i]; vs[i]=x; ss+=x; qs+=x*x; }
        #pragma unroll
        for (int off=32; off>=1; off>>=1){
            sa += __shfl_xor(sa,off); qa += __shfl_xor(qa,off);
            ss += __shfl_xor(ss,off); qs += __shfl_xor(qs,off);
        }
        int w = t>>6;
        if ((t&63)==0){ red[w*4+0]=sa; red[w*4+1]=qa; red[w*4+2]=ss; red[w*4+3]=qs; }
        __syncthreads();
        sa = red[0]+red[4]+red[8]+red[12];
        qa = red[1]+red[5]+red[9]+red[13];
        ss = red[2]+red[6]+red[10]+red[14];
        qs = red[3]+red[7]+red[11]+red[15];
        float mua=sa*(1.f/768.f), mus=ss*(1.f/768.f);
        float rva=rsqrtf(fmaxf(qa*(1.f/768.f)-mua*mua,0.f)+1e-5f);
        float rvs=rsqrtf(fmaxf(qs*(1.f/768.f)-mus*mus,0.f)+1e-5f);
        #pragma unroll
        for (int i=0;i<3;i++){
            int c=t+256*i;
            size_t idx=(size_t)r*DIMM+c;
            a_ln[idx]=(va[i]-mua)*rva;
            float sv=(vs[i]-mus)*rvs*sw[c];
            u16 h,l; bfsplit(sv,h,l);
            shi[idx]=h; slo[idx]=l;
        }
        return;
    }
    if (bid < 3200){
        int b = bid - 2048;
        int n0 = (b%12)*64, k0 = ((b/12)%12)*64, z = b/144;
        const float* src;
        switch(z){
            case 0: src=w0; break; case 1: src=w1; break;
            case 2: src=w2; break; case 3: src=w3; break;
            case 4: src=w4; break; case 5: src=w5; break;
            case 6: src=w6; break; default: src=w7; break;
        }
        #pragma unroll
        for (int it=0; it<4; it++){
            int idx = t + it*256;
            int kr = idx>>4, nc = (idx&15)*4;
            float4 v = *(const float4*)(src + (size_t)(k0+kr)*DIMM + n0+nc);
            *(float4*)(&tile[kr][nc]) = v;
        }
        __syncthreads();
        u16* wth = wt + (size_t)z*2*589824;
        u16* wtl = wth + 589824;
        #pragma unroll
        for (int it=0; it<4; it++){
            int idx = t + it*256;
            int nr = idx>>4, kc = (idx&15)*4;
            ushort4 h4, l4;
            u16 h,l;
            bfsplit(tile[kc+0][nr],h,l); h4.x=h; l4.x=l;
            bfsplit(tile[kc+1][nr],h,l); h4.y=h; l4.y=l;
            bfsplit(tile[kc+2][nr],h,l); h4.z=h; l4.z=l;
            bfsplit(tile[kc+3][nr],h,l); h4.w=h; l4.w=l;
            size_t o = (size_t)(n0+nr)*DIMM + k0+kc;
            *(ushort4*)(wth + o) = h4;
            *(ushort4*)(wtl + o) = l4;
        }
        return;
    }
    for (int i=t;i<2048;i+=256) wpc[i] = plnw[i>>4]*wp[i];
    if (t<16){
        float cs=0.f,b0=0.f;
        for (int c=0;c<128;c++){ cs += plnw[c]*wp[c*16+t]; b0 += plnb[c]*wp[c*16+t]; }
        csb[t]=cs; csb[16+t]=b0;
    }
}

// ---------------------------------------------------------------------------
// GEMM tile body, R10 structure (two barriers, no reg prefetch — proven best).
// ---------------------------------------------------------------------------
template<int NB>
__device__ __forceinline__ void gemm_tile(
    const u16* __restrict__ Ahp, const u16* __restrict__ Alp,
    const u16* __restrict__ B0h, const u16* __restrict__ B0l,
    const u16* __restrict__ B1h, const u16* __restrict__ B1l,
    int m0, int n0, int t,
    u16 (&lA)[2][128][40], u16 (&lB)[NB][2][64][40],
    f32x4 (&acc)[NB][2][4])
{
    int lane = t&63, w = t>>6;
    int fr = lane&15, fg = lane>>4;
    for (int k0=0; k0<DIMM; k0+=32){
        #pragma unroll
        for (int it=0; it<4; it++){
            int s = t + it*256;
            int pl = s>>9, s2 = s&511;
            int row = s2>>2, seg = (s2&3)*8;
            *(int4*)(&lA[pl][row][seg]) =
                *(const int4*)((pl?Alp:Ahp) + (size_t)(m0+row)*DIMM + k0 + seg);
        }
        #pragma unroll
        for (int i=0;i<NB;i++){
            const u16* bh = i ? B1h : B0h;
            const u16* bl = i ? B1l : B0l;
            #pragma unroll
            for (int it=0; it<2; it++){
                int s = t + it*256;
                int pl = s>>8, s2 = s&255;
                int row = s2>>2, seg = (s2&3)*8;
                *(int4*)(&lB[i][pl][row][seg]) =
                    *(const int4*)((pl?bl:bh) + (size_t)(n0+row)*DIMM + k0 + seg);
            }
        }
        __syncthreads();
        short8 a_h0 = *(const short8*)(&lA[0][w*32+fr][fg*8]);
        short8 a_h1 = *(const short8*)(&lA[0][w*32+16+fr][fg*8]);
        short8 a_l0 = *(const short8*)(&lA[1][w*32+fr][fg*8]);
        short8 a_l1 = *(const short8*)(&lA[1][w*32+16+fr][fg*8]);
        #pragma unroll
        for (int nf=0;nf<4;nf++){
            #pragma unroll
            for (int i=0;i<NB;i++){
                short8 b_h = *(const short8*)(&lB[i][0][nf*16+fr][fg*8]);
                short8 b_l = *(const short8*)(&lB[i][1][nf*16+fr][fg*8]);
                acc[i][0][nf] = __builtin_amdgcn_mfma_f32_16x16x32_bf16(a_h0, b_h, acc[i][0][nf], 0,0,0);
                acc[i][0][nf] = __builtin_amdgcn_mfma_f32_16x16x32_bf16(a_h0, b_l, acc[i][0][nf], 0,0,0);
                acc[i][0][nf] = __builtin_amdgcn_mfma_f32_16x16x32_bf16(a_l0, b_h, acc[i][0][nf], 0,0,0);
                acc[i][1][nf] = __builtin_amdgcn_mfma_f32_16x16x32_bf16(a_h1, b_h, acc[i][1][nf], 0,0,0);
                acc[i][1][nf] = __builtin_amdgcn_mfma_f32_16x16x32_bf16(a_h1, b_l, acc[i][1][nf], 0,0,0);
                acc[i][1][nf] = __builtin_amdgcn_mfma_f32_16x16x32_bf16(a_l1, b_h, acc[i][1][nf], 0,0,0);
            }
        }
        __syncthreads();
    }
}

// ---------------------------------------------------------------------------
// K2: fused {pair_bias (blocks 0..4095), G1 adaln GEMM (4096..4287)} — R12 order
// ---------------------------------------------------------------------------
__device__ __forceinline__ void fma16(float yc, const float* __restrict__ wrow,
                                      float acc[16])
{
    const float4* wr = (const float4*)wrow;
    float4 w0=wr[0], w1=wr[1], w2=wr[2], w3=wr[3];
    acc[0]+=yc*w0.x;  acc[1]+=yc*w0.y;  acc[2]+=yc*w0.z;  acc[3]+=yc*w0.w;
    acc[4]+=yc*w1.x;  acc[5]+=yc*w1.y;  acc[6]+=yc*w1.z;  acc[7]+=yc*w1.w;
    acc[8]+=yc*w2.x;  acc[9]+=yc*w2.y;  acc[10]+=yc*w2.z; acc[11]+=yc*w2.w;
    acc[12]+=yc*w3.x; acc[13]+=yc*w3.y; acc[14]+=yc*w3.z; acc[15]+=yc*w3.w;
}

__global__ __launch_bounds__(256) void k_pb_g1(
    const float* __restrict__ pair, const float* __restrict__ wpc,
    const float* __restrict__ csb, const float* __restrict__ mask,
    u16* __restrict__ pb,
    const u16* __restrict__ shi, const u16* __restrict__ slo,
    const u16* __restrict__ gwh, const u16* __restrict__ gwl,
    const u16* __restrict__ skh, const u16* __restrict__ skl,
    const float* __restrict__ gate_b, const float* __restrict__ a_ln,
    u16* __restrict__ ahi, u16* __restrict__ alo)
{
    __shared__ u16 lA[2][128][40];
    __shared__ u16 lB[2][2][64][40];
    int bid = blockIdx.x, t = threadIdx.x;
    if (bid < 4096){
        // ---- pair_bias (R9/R12 verified form) ----
        int row = bid*256 + t;
        int j = row & (NN-1);
        const float4* x4 = (const float4*)(pair + (size_t)row*CPAIR);
        float s=0.f, sq=0.f;
        float acc[16];
        #pragma unroll
        for (int h=0;h<16;h++) acc[h]=0.f;
        #pragma unroll 4
        for (int i=0;i<32;i++){
            float4 v = x4[i];
            s  += v.x+v.y+v.z+v.w;
            sq += v.x*v.x+v.y*v.y+v.z*v.z+v.w*v.w;
            fma16(v.x, wpc + (4*i+0)*16, acc);
            fma16(v.y, wpc + (4*i+1)*16, acc);
            fma16(v.z, wpc + (4*i+2)*16, acc);
            fma16(v.w, wpc + (4*i+3)*16, acc);
        }
        float mu = s*(1.f/128.f);
        float rs = rsqrtf(fmaxf(sq*(1.f/128.f)-mu*mu,0.f)+1e-5f);
        float mb = 1e8f*(mask[j]-1.f);
        #pragma unroll
        for (int h=0;h<16;h++){
            float outv = (acc[h]-mu*csb[h])*rs + csb[16+h] + mb;
            pb[((size_t)h<<20) + row] = f2bf(outv);
        }
        return;
    }
    // ---- G1 ----
    int b = bid - 4096;
    int m0 = (b&15)*128, n0 = (b>>4)*64;
    int lane = t&63, w = t>>6;
    int fr = lane&15, fg = lane>>4;
    f32x4 acc[2][2][4];
    #pragma unroll
    for (int i=0;i<2;i++)
        #pragma unroll
        for (int mf=0;mf<2;mf++)
            #pragma unroll
            for (int nf=0;nf<4;nf++) acc[i][mf][nf] = (f32x4){0.f,0.f,0.f,0.f};
    gemm_tile<2>(shi, slo, gwh, gwl, skh, skl, m0, n0, t, lA, lB, acc);
    #pragma unroll
    for (int mf=0;mf<2;mf++){
        #pragma unroll
        for (int nf=0;nf<4;nf++){
            #pragma unroll
            for (int r=0;r<4;r++){
                int row = m0 + w*32 + mf*16 + fg*4 + r;
                int col = n0 + nf*16 + fr;
                size_t idx = (size_t)row*DIMM + col;
                float c0 = acc[0][mf][nf][r];
                float c1 = acc[1][mf][nf][r];
                float v = sigm(c0 + gate_b[col]) * a_ln[idx] + c1;
                u16 h,l; bfsplit(v,h,l); ahi[idx]=h; alo[idx]=l;
            }
        }
    }
}

// ---------------------------------------------------------------------------
// bf16x2-split MFMA GEMM (EPI 3/4 paths) — R10 structure
// ---------------------------------------------------------------------------
template<int EPI>
__global__ __launch_bounds__(256) void k_gemm(
    const u16* __restrict__ Ahp, const u16* __restrict__ Alp,
    const u16* __restrict__ B0h, const u16* __restrict__ B0l,
    const float* __restrict__ e0,
    float* __restrict__ o0,
    u16* __restrict__ oh, u16* __restrict__ ol)
{
    __shared__ u16 lA[2][128][40];
    __shared__ u16 lB[1][2][64][40];
    int m0 = blockIdx.x*128, n0 = blockIdx.y*64;
    int t = threadIdx.x, lane = t&63, w = t>>6;
    int fr = lane&15, fg = lane>>4;
    f32x4 acc[1][2][4];
    #pragma unroll
    for (int mf=0;mf<2;mf++)
        #pragma unroll
        for (int nf=0;nf<4;nf++) acc[0][mf][nf] = (f32x4){0.f,0.f,0.f,0.f};

    gemm_tile<1>(Ahp, Alp, B0h, B0l, nullptr, nullptr, m0, n0, t, lA, lB, acc);

    #pragma unroll
    for (int mf=0;mf<2;mf++){
        #pragma unroll
        for (int nf=0;nf<4;nf++){
            #pragma unroll
            for (int r=0;r<4;r++){
                int row = m0 + w*32 + mf*16 + fg*4 + r;
                int col = n0 + nf*16 + fr;
                size_t idx = (size_t)row*DIMM + col;
                float c0 = acc[0][mf][nf][r];
                if (EPI==3){
                    float v = c0 + e0[col];
                    u16 h,l; bfsplit(v,h,l); oh[idx]=h; ol[idx]=l;
                } else {
                    float o2v = bf2f(Ahp[idx]) + bf2f(Alp[idx]);
                    o0[idx] = sigm(c0 + e0[col]) * o2v;
                }
            }
        }
    }
}

// ---------------------------------------------------------------------------
// merged q/k (z=0) + v/gate (z=1) GEMM — R10 body
// ---------------------------------------------------------------------------
__global__ __launch_bounds__(256) void k_gemm_qkvg(
    const u16* __restrict__ Ahp, const u16* __restrict__ Alp,
    const u16* __restrict__ wqh, const u16* __restrict__ wql,
    const u16* __restrict__ wkh, const u16* __restrict__ wkl,
    const u16* __restrict__ wvh, const u16* __restrict__ wvl,
    const u16* __restrict__ wgh, const u16* __restrict__ wgl,
    const float* __restrict__ bgate,
    u16* __restrict__ qah, u16* __restrict__ qal,
    u16* __restrict__ kah, u16* __restrict__ kal,
    u16* __restrict__ vth, u16* __restrict__ vtl,
    float* __restrict__ g)
{
    __shared__ u16 lA[2][128][40];
    __shared__ u16 lB[2][2][64][40];
    int m0 = blockIdx.x*128, n0 = blockIdx.y*64;
    int z = blockIdx.z;
    const u16* B0h = z ? wvh : wqh;
    const u16* B0l = z ? wvl : wql;
    const u16* B1h = z ? wgh : wkh;
    const u16* B1l = z ? wgl : wkl;
    int t = threadIdx.x, lane = t&63, w = t>>6;
    int fr = lane&15, fg = lane>>4;
    f32x4 acc[2][2][4];
    #pragma unroll
    for (int i=0;i<2;i++)
        #pragma unroll
        for (int mf=0;mf<2;mf++)
            #pragma unroll
            for (int nf=0;nf<4;nf++) acc[i][mf][nf] = (f32x4){0.f,0.f,0.f,0.f};

    gemm_tile<2>(Ahp, Alp, B0h, B0l, B1h, B1l, m0, n0, t, lA, lB, acc);

    #pragma unroll
    for (int mf=0;mf<2;mf++){
        #pragma unroll
        for (int nf=0;nf<4;nf++){
            #pragma unroll
            for (int r=0;r<4;r++){
                int row = m0 + w*32 + mf*16 + fg*4 + r;
                int col = n0 + nf*16 + fr;
                size_t idx = (size_t)row*DIMM + col;
                int s2 = row>>10, n = row&(NN-1);
                int hh2 = col/CH, cc = col-hh2*CH;
                float c0 = acc[0][mf][nf][r];
                float c1 = acc[1][mf][nf][r];
                if (z==0){
                    size_t pidx = ((size_t)(s2*HEADS+hh2)*NN + n)*CH + cc;
                    u16 hx,lx;
                    bfsplit(c0*0.14433756729740643f, hx,lx);
                    qah[pidx]=hx; qal[pidx]=lx;
                    bfsplit(c1,hx,lx);
                    kah[pidx]=hx; kal[pidx]=lx;
                } else {
                    size_t vidx = ((size_t)(s2*HEADS+hh2)*CH + cc)*NN + n;
                    u16 hx,lx; bfsplit(c0,hx,lx);
                    vth[vidx]=hx; vtl[vidx]=lx;
                    g[idx] = sigm(c1 + bgate[col]);
                }
            }
        }
    }
}

// ---------------------------------------------------------------------------
// flash attention, LDS-staging-free: all MFMA fragments are contiguous 16B in
// the producer layouts, so each wave loads them straight from global (L1/L2
// absorbs the 4-wave redundancy). Only the same-wave P-transpose uses LDS.
// NO __syncthreads anywhere -> waves fully independent; occupancy 2x.
// Pad cols 48..63 of Q/K handled by zeroing chunk-1 frags for fg>=2.
// ---------------------------------------------------------------------------
__global__ __launch_bounds__(256) void k_attn(
    const u16* __restrict__ qah, const u16* __restrict__ qal,
    const u16* __restrict__ kah, const u16* __restrict__ kal,
    const u16* __restrict__ vth, const u16* __restrict__ vtl,
    const u16* __restrict__ pb, const float* __restrict__ g,
    u16* __restrict__ oghi, u16* __restrict__ oglo)
{
    __shared__ u16 lP[4][16][72];
    int t = threadIdx.x, lane = t&63, w = t>>6;
    int fr = lane&15, fg = lane>>4;
    int m0 = blockIdx.x*64;
    int sh = blockIdx.y, s = sh>>4, h = sh&15;
    size_t qkbase = (size_t)sh*NN*CH;   // [s][h][n][48]
    size_t vbase  = (size_t)sh*CH*NN;   // [s][h][c][n]
    bool lo_ok = (fg < 2);              // cols 32+fg*8 < 48 valid

    // Q fragments direct from global (A-operand rows = q rows)
    const u16* qrow_h = qah + qkbase + (size_t)(m0 + w*16 + fr)*CH;
    const u16* qrow_l = qal + qkbase + (size_t)(m0 + w*16 + fr)*CH;
    short8 aqh0 = *(const short8*)(qrow_h + fg*8);
    short8 aql0 = *(const short8*)(qrow_l + fg*8);
    short8 aqh1 = lo_ok ? *(const short8*)(qrow_h + 32 + fg*8) : zero8();
    short8 aql1 = lo_ok ? *(const short8*)(qrow_l + 32 + fg*8) : zero8();

    f32x4 acc_o[3];
    #pragma unroll
    for (int i=0;i<3;i++) acc_o[i]=(f32x4){0.f,0.f,0.f,0.f};
    float m[4], l[4];
    #pragma unroll
    for (int r=0;r<4;r++){ m[r]=-3e38f; l[r]=0.f; }
    int qrow_base = m0 + w*16 + fg*4;
    const u16* pbq = pb + ((size_t)h<<20) + (size_t)qrow_base*NN + fr;

    for (int kt=0; kt<16; kt++){
        int k0 = kt*64;
        // QK^T: K B-fragments direct from global
        f32x4 sc[4];
        #pragma unroll
        for (int nf=0;nf<4;nf++){
            const u16* krow_h = kah + qkbase + (size_t)(k0 + nf*16 + fr)*CH;
            const u16* krow_l = kal + qkbase + (size_t)(k0 + nf*16 + fr)*CH;
            short8 bh0 = *(const short8*)(krow_h + fg*8);
            short8 bl0 = *(const short8*)(krow_l + fg*8);
            short8 bh1 = lo_ok ? *(const short8*)(krow_h + 32 + fg*8) : zero8();
            short8 bl1 = lo_ok ? *(const short8*)(krow_l + 32 + fg*8) : zero8();
            f32x4 a = (f32x4){0.f,0.f,0.f,0.f};
            a = __builtin_amdgcn_mfma_f32_16x16x32_bf16(aqh0, bh0, a, 0,0,0);
            a = __builtin_amdgcn_mfma_f32_16x16x32_bf16(aqh1, bh1, a, 0,0,0);
            a = __builtin_amdgcn_mfma_f32_16x16x32_bf16(aqh0, bl0, a, 0,0,0);
            a = __builtin_amdgcn_mfma_f32_16x16x32_bf16(aqh1, bl1, a, 0,0,0);
            a = __builtin_amdgcn_mfma_f32_16x16x32_bf16(aql0, bh0, a, 0,0,0);
            a = __builtin_amdgcn_mfma_f32_16x16x32_bf16(aql1, bh1, a, 0,0,0);
            sc[nf]=a;
        }
        u16 pbv[4][4];
        #pragma unroll
        for (int r=0;r<4;r++)
            #pragma unroll
            for (int nf=0;nf<4;nf++)
                pbv[r][nf] = pbq[(size_t)r*NN + k0 + nf*16];
        // + pair bias, online softmax (rows spread over fr lanes, width-16)
        float mn[4];
        #pragma unroll
        for (int r=0;r<4;r++){
            float v0 = sc[0][r]+bf2f(pbv[r][0]);
            float v1 = sc[1][r]+bf2f(pbv[r][1]);
            float v2 = sc[2][r]+bf2f(pbv[r][2]);
            float v3 = sc[3][r]+bf2f(pbv[r][3]);
            sc[0][r]=v0; sc[1][r]=v1; sc[2][r]=v2; sc[3][r]=v3;
            float mx = fmaxf(fmaxf(v0,v1),fmaxf(v2,v3));
            mx = fmaxf(mx, __shfl_xor(mx,1,64));
            mx = fmaxf(mx, __shfl_xor(mx,2,64));
            mx = fmaxf(mx, __shfl_xor(mx,4,64));
            mx = fmaxf(mx, __shfl_xor(mx,8,64));
            mn[r]=mx;
        }
        #pragma unroll
        for (int r=0;r<4;r++){
            float mnew = fmaxf(m[r], mn[r]);
            float corr = __expf(m[r]-mnew);
            m[r]=mnew;
            float ps=0.f;
            #pragma unroll
            for (int nf=0;nf<4;nf++){
                float p = __expf(sc[nf][r]-mnew);
                u16 pu = f2bf(p);
                ps += bf2f(pu);
                lP[w][fg*4+r][nf*16+fr] = pu;
            }
            // l[r] is a per-lane PARTIAL row-sum; corr is lane-uniform within
            // the row group, so the final cross-lane sum commutes (epilogue).
            l[r] = l[r]*corr + ps;
            acc_o[0][r]*=corr; acc_o[1][r]*=corr; acc_o[2][r]*=corr;
        }
        // PV: P from same-wave LDS transpose; V B-fragments direct from global
        short8 pa0 = *(const short8*)(&lP[w][fr][fg*8]);
        short8 pa1 = *(const short8*)(&lP[w][fr][32+fg*8]);
        #pragma unroll
        for (int cf=0;cf<3;cf++){
            const u16* vrow_h = vth + vbase + (size_t)(cf*16+fr)*NN + k0;
            const u16* vrow_l = vtl + vbase + (size_t)(cf*16+fr)*NN + k0;
            short8 vh0 = *(const short8*)(vrow_h + fg*8);
            short8 vh1 = *(const short8*)(vrow_h + 32 + fg*8);
            short8 vl0 = *(const short8*)(vrow_l + fg*8);
            short8 vl1 = *(const short8*)(vrow_l + 32 + fg*8);
            acc_o[cf] = __builtin_amdgcn_mfma_f32_16x16x32_bf16(pa0, vh0, acc_o[cf], 0,0,0);
            acc_o[cf] = __builtin_amdgcn_mfma_f32_16x16x32_bf16(pa1, vh1, acc_o[cf], 0,0,0);
            acc_o[cf] = __builtin_amdgcn_mfma_f32_16x16x32_bf16(pa0, vl0, acc_o[cf], 0,0,0);
            acc_o[cf] = __builtin_amdgcn_mfma_f32_16x16x32_bf16(pa1, vl1, acc_o[cf], 0,0,0);
        }
    }
    // epilogue: reduce lane-partial l across the 16 fr-lanes, gate, store
    float rl[4];
    #pragma unroll
    for (int r=0;r<4;r++){
        float lv = l[r];
        lv += __shfl_xor(lv,1,64);
        lv += __shfl_xor(lv,2,64);
        lv += __shfl_xor(lv,4,64);
        lv += __shfl_xor(lv,8,64);
        rl[r] = 1.f/lv;
    }
    #pragma unroll
    for (int cf=0;cf<3;cf++){
        #pragma unroll
        for (int r=0;r<4;r++){
            size_t orow = ((size_t)(s*NN + m0 + w*16 + fg*4 + r))*DIMM + h*CH + cf*16 + fr;
            float val = acc_o[cf][r]*rl[r] * g[orow];
            u16 hh,ll; bfsplit(val,hh,ll);
            oghi[orow]=hh; oglo[orow]=ll;
        }
    }
}

// ---------------------------------------------------------------------------
extern "C" void kernel_launch(void* const* d_in, const int* in_sizes, int n_in,
                              void* d_out, int out_size, void* d_ws, size_t ws_size,
                              hipStream_t stream)
{
    const float* srep   = (const float*)d_in[0];
    const float* sproj  = (const float*)d_in[1];
    const float* pair   = (const float*)d_in[2];
    const float* mask   = (const float*)d_in[3];
    const float* s_w    = (const float*)d_in[4];
    const float* gate_w = (const float*)d_in[5];
    const float* gate_b = (const float*)d_in[6];
    const float* skip_w = (const float*)d_in[7];
    const float* wq     = (const float*)d_in[8];
    const float* wk     = (const float*)d_in[9];
    const float* wv     = (const float*)d_in[10];
    const float* w_gate = (const float*)d_in[11];
    const float* b_gate = (const float*)d_in[12];
    const float* wo     = (const float*)d_in[13];
    const float* bo     = (const float*)d_in[14];
    const float* plnw   = (const float*)d_in[15];
    const float* plnb   = (const float*)d_in[16];
    const float* w_pair = (const float*)d_in[17];
    const float* w_out  = (const float*)d_in[18];
    const float* b_out  = (const float*)d_in[19];
    float* out = (float*)d_out;

    const size_t T  = (size_t)NROWS*DIMM;       // 1,572,864
    const size_t W  = (size_t)DIMM*DIMM;        // 589,824
    const size_t PB = (size_t)HEADS*NN*NN;      // 16,777,216

    char* p = (char*)d_ws;
    float* a_ln = (float*)p; p += T*4;
    float* g    = (float*)p; p += T*4;
    float* wpc  = (float*)p; p += 2048*4;
    float* csb  = (float*)p; p += 32*4;
    u16* shi  = (u16*)p; p += T*2;
    u16* slo  = (u16*)p; p += T*2;
    u16* ahi  = (u16*)p; p += T*2;
    u16* alo  = (u16*)p; p += T*2;
    u16* oghi = (u16*)p; p += T*2;
    u16* oglo = (u16*)p; p += T*2;
    u16* o2hi = (u16*)p; p += T*2;
    u16* o2lo = (u16*)p; p += T*2;
    u16* qah  = (u16*)p; p += T*2;
    u16* qal  = (u16*)p; p += T*2;
    u16* kah  = (u16*)p; p += T*2;
    u16* kal  = (u16*)p; p += T*2;
    u16* vth  = (u16*)p; p += T*2;
    u16* vtl  = (u16*)p; p += T*2;
    u16* pbias= (u16*)p; p += PB*2;
    u16* wt   = (u16*)p; p += 16*W*2;

    #define WH(i) (wt + (size_t)(i)*2*W)
    #define WL(i) (wt + (size_t)(i)*2*W + W)

    // K1: fused ln_single + wsplit + pair_pre
    k_pre<<<2048+1152+1, 256, 0, stream>>>(
        srep, sproj, s_w, a_ln, shi, slo,
        gate_w, skip_w, wq, wk, wv, w_gate, wo, w_out, wt,
        plnw, plnb, w_pair, wpc, csb);

    // K2: fused pair_bias + G1 (R12 order)
    k_pb_g1<<<4096+192, 256, 0, stream>>>(
        pair, wpc, csb, mask, pbias,
        shi, slo, WH(0), WL(0), WH(1), WL(1), gate_b, a_ln, ahi, alo);

    // K3: merged q/k + v/gate
    k_gemm_qkvg<<<dim3(NROWS/128, DIMM/64, 2), 256, 0, stream>>>(
        ahi, alo, WH(2), WL(2), WH(3), WL(3), WH(4), WL(4), WH(5), WL(5),
        b_gate, qah, qal, kah, kal, vth, vtl, g);

    // K4: attention (LDS-staging-free)
    k_attn<<<dim3(NN/64, 2*HEADS), 256, 0, stream>>>(
        qah, qal, kah, kal, vth, vtl, pbias, g, oghi, oglo);

    dim3 gg(NROWS/128, DIMM/64);
    // K5: o2 = og@wo + bo
    k_gemm<3><<<gg, 256, 0, stream>>>(oghi, oglo, WH(6), WL(6), bo,
                                      nullptr, o2hi, o2lo);
    // K6: out = sigm(o2@w_out + b_out) * o2
    k_gemm<4><<<gg, 256, 0, stream>>>(o2hi, o2lo, WH(7), WL(7), b_out,
                                      out, nullptr, nullptr);
    #undef WH
    #undef WL
}

// Round 18
// 371.341 us; speedup vs baseline: 1.0792x; 1.0792x over previous
//
#include <hip/hip_runtime.h>

#define NROWS 2048      // S*N rows
#define NN    1024
#define DIMM  768
#define HEADS 16
#define CH    48
#define CPAIR 128

typedef unsigned short u16;
typedef unsigned int   u32;
typedef __attribute__((ext_vector_type(8))) short short8;
typedef __attribute__((ext_vector_type(4))) float f32x4;

__device__ __forceinline__ float sigm(float x){ return 1.0f/(1.0f+__expf(-x)); }
__device__ __forceinline__ u16 f2bf(float x){
    u32 u = __float_as_uint(x);
    u32 r = u + 0x7FFFu + ((u>>16)&1u);
    return (u16)(r>>16);
}
__device__ __forceinline__ float bf2f(u16 h){ return __uint_as_float(((u32)h)<<16); }
__device__ __forceinline__ void bfsplit(float x, u16& hi, u16& lo){
    hi = f2bf(x);
    lo = f2bf(x - bf2f(hi));
}

// ---------------------------------------------------------------------------
// K1: fused {ln_single (blocks 0..2047), wsplit (2048..3199), pair_pre (3200)}
// ---------------------------------------------------------------------------
__global__ __launch_bounds__(256) void k_pre(
    const float* __restrict__ srep, const float* __restrict__ sproj,
    const float* __restrict__ sw, float* __restrict__ a_ln,
    u16* __restrict__ shi, u16* __restrict__ slo,
    const float* __restrict__ w0, const float* __restrict__ w1,
    const float* __restrict__ w2, const float* __restrict__ w3,
    const float* __restrict__ w4, const float* __restrict__ w5,
    const float* __restrict__ w6, const float* __restrict__ w7,
    u16* __restrict__ wt,
    const float* __restrict__ plnw, const float* __restrict__ plnb,
    const float* __restrict__ wp, float* __restrict__ wpc,
    float* __restrict__ csb)
{
    __shared__ float tile[64][68];
    __shared__ float red[16];
    int bid = blockIdx.x, t = threadIdx.x;
    if (bid < 2048){
        // ---- ln_single, r = bid ----
        int r = bid;
        const float* xa = srep  + (size_t)r*DIMM;
        const float* xs = sproj + (size_t)r*DIMM;
        float va[3], vs[3];
        float sa=0.f,qa=0.f,ss=0.f,qs=0.f;
        #pragma unroll
        for (int i=0;i<3;i++){ float x=xa[t+256*i]; va[i]=x; sa+=x; qa+=x*x; }
        #pragma unroll
        for (int i=0;i<3;i++){ float x=xs[t+256*i]; vs[i]=x; ss+=x; qs+=x*x; }
        #pragma unroll
        for (int off=32; off>=1; off>>=1){
            sa += __shfl_xor(sa,off); qa += __shfl_xor(qa,off);
            ss += __shfl_xor(ss,off); qs += __shfl_xor(qs,off);
        }
        int w = t>>6;
        if ((t&63)==0){ red[w*4+0]=sa; red[w*4+1]=qa; red[w*4+2]=ss; red[w*4+3]=qs; }
        __syncthreads();
        sa = red[0]+red[4]+red[8]+red[12];
        qa = red[1]+red[5]+red[9]+red[13];
        ss = red[2]+red[6]+red[10]+red[14];
        qs = red[3]+red[7]+red[11]+red[15];
        float mua=sa*(1.f/768.f), mus=ss*(1.f/768.f);
        float rva=rsqrtf(fmaxf(qa*(1.f/768.f)-mua*mua,0.f)+1e-5f);
        float rvs=rsqrtf(fmaxf(qs*(1.f/768.f)-mus*mus,0.f)+1e-5f);
        #pragma unroll
        for (int i=0;i<3;i++){
            int c=t+256*i;
            size_t idx=(size_t)r*DIMM+c;
            a_ln[idx]=(va[i]-mua)*rva;
            float sv=(vs[i]-mus)*rvs*sw[c];
            u16 h,l; bfsplit(sv,h,l);
            shi[idx]=h; slo[idx]=l;
        }
        return;
    }
    if (bid < 3200){
        // ---- wsplit, b = bid-2048 in [0,1152): x=b%12, y=(b/12)%12, z=b/144
        int b = bid - 2048;
        int n0 = (b%12)*64, k0 = ((b/12)%12)*64, z = b/144;
        const float* src;
        switch(z){
            case 0: src=w0; break; case 1: src=w1; break;
            case 2: src=w2; break; case 3: src=w3; break;
            case 4: src=w4; break; case 5: src=w5; break;
            case 6: src=w6; break; default: src=w7; break;
        }
        #pragma unroll
        for (int it=0; it<4; it++){
            int idx = t + it*256;
            int kr = idx>>4, nc = (idx&15)*4;
            float4 v = *(const float4*)(src + (size_t)(k0+kr)*DIMM + n0+nc);
            *(float4*)(&tile[kr][nc]) = v;
        }
        __syncthreads();
        u16* wth = wt + (size_t)z*2*589824;
        u16* wtl = wth + 589824;
        #pragma unroll
        for (int it=0; it<4; it++){
            int idx = t + it*256;
            int nr = idx>>4, kc = (idx&15)*4;
            ushort4 h4, l4;
            u16 h,l;
            bfsplit(tile[kc+0][nr],h,l); h4.x=h; l4.x=l;
            bfsplit(tile[kc+1][nr],h,l); h4.y=h; l4.y=l;
            bfsplit(tile[kc+2][nr],h,l); h4.z=h; l4.z=l;
            bfsplit(tile[kc+3][nr],h,l); h4.w=h; l4.w=l;
            size_t o = (size_t)(n0+nr)*DIMM + k0+kc;
            *(ushort4*)(wth + o) = h4;
            *(ushort4*)(wtl + o) = l4;
        }
        return;
    }
    // ---- pair_pre (1 block) ----
    for (int i=t;i<2048;i+=256) wpc[i] = plnw[i>>4]*wp[i];
    if (t<16){
        float cs=0.f,b0=0.f;
        for (int c=0;c<128;c++){ cs += plnw[c]*wp[c*16+t]; b0 += plnb[c]*wp[c*16+t]; }
        csb[t]=cs; csb[16+t]=b0;
    }
}

// ---------------------------------------------------------------------------
// GEMM tile body, R10 structure (two barriers, no reg prefetch — proven best).
// Tile M=128 x N=64, BK=32, 4 waves; wave owns 32x64.
// ---------------------------------------------------------------------------
template<int NB>
__device__ __forceinline__ void gemm_tile(
    const u16* __restrict__ Ahp, const u16* __restrict__ Alp,
    const u16* __restrict__ B0h, const u16* __restrict__ B0l,
    const u16* __restrict__ B1h, const u16* __restrict__ B1l,
    int m0, int n0, int t,
    u16 (&lA)[2][128][40], u16 (&lB)[NB][2][64][40],
    f32x4 (&acc)[NB][2][4])
{
    int lane = t&63, w = t>>6;
    int fr = lane&15, fg = lane>>4;
    for (int k0=0; k0<DIMM; k0+=32){
        #pragma unroll
        for (int it=0; it<4; it++){
            int s = t + it*256;
            int pl = s>>9, s2 = s&511;
            int row = s2>>2, seg = (s2&3)*8;
            *(int4*)(&lA[pl][row][seg]) =
                *(const int4*)((pl?Alp:Ahp) + (size_t)(m0+row)*DIMM + k0 + seg);
        }
        #pragma unroll
        for (int i=0;i<NB;i++){
            const u16* bh = i ? B1h : B0h;
            const u16* bl = i ? B1l : B0l;
            #pragma unroll
            for (int it=0; it<2; it++){
                int s = t + it*256;
                int pl = s>>8, s2 = s&255;
                int row = s2>>2, seg = (s2&3)*8;
                *(int4*)(&lB[i][pl][row][seg]) =
                    *(const int4*)((pl?bl:bh) + (size_t)(n0+row)*DIMM + k0 + seg);
            }
        }
        __syncthreads();
        short8 a_h0 = *(const short8*)(&lA[0][w*32+fr][fg*8]);
        short8 a_h1 = *(const short8*)(&lA[0][w*32+16+fr][fg*8]);
        short8 a_l0 = *(const short8*)(&lA[1][w*32+fr][fg*8]);
        short8 a_l1 = *(const short8*)(&lA[1][w*32+16+fr][fg*8]);
        #pragma unroll
        for (int nf=0;nf<4;nf++){
            #pragma unroll
            for (int i=0;i<NB;i++){
                short8 b_h = *(const short8*)(&lB[i][0][nf*16+fr][fg*8]);
                short8 b_l = *(const short8*)(&lB[i][1][nf*16+fr][fg*8]);
                acc[i][0][nf] = __builtin_amdgcn_mfma_f32_16x16x32_bf16(a_h0, b_h, acc[i][0][nf], 0,0,0);
                acc[i][0][nf] = __builtin_amdgcn_mfma_f32_16x16x32_bf16(a_h0, b_l, acc[i][0][nf], 0,0,0);
                acc[i][0][nf] = __builtin_amdgcn_mfma_f32_16x16x32_bf16(a_l0, b_h, acc[i][0][nf], 0,0,0);
                acc[i][1][nf] = __builtin_amdgcn_mfma_f32_16x16x32_bf16(a_h1, b_h, acc[i][1][nf], 0,0,0);
                acc[i][1][nf] = __builtin_amdgcn_mfma_f32_16x16x32_bf16(a_h1, b_l, acc[i][1][nf], 0,0,0);
                acc[i][1][nf] = __builtin_amdgcn_mfma_f32_16x16x32_bf16(a_l1, b_h, acc[i][1][nf], 0,0,0);
            }
        }
        __syncthreads();
    }
}

// ---------------------------------------------------------------------------
// K2: fused {pair_bias (blocks 0..4095), G1 adaln GEMM (4096..4287)}
// pair_bias: ROW-PER-LANE + merged loop (R9, verified). G1: EPI0 epilogue.
// ---------------------------------------------------------------------------
__device__ __forceinline__ void fma16(float yc, const float* __restrict__ wrow,
                                      float acc[16])
{
    const float4* wr = (const float4*)wrow;
    float4 w0=wr[0], w1=wr[1], w2=wr[2], w3=wr[3];
    acc[0]+=yc*w0.x;  acc[1]+=yc*w0.y;  acc[2]+=yc*w0.z;  acc[3]+=yc*w0.w;
    acc[4]+=yc*w1.x;  acc[5]+=yc*w1.y;  acc[6]+=yc*w1.z;  acc[7]+=yc*w1.w;
    acc[8]+=yc*w2.x;  acc[9]+=yc*w2.y;  acc[10]+=yc*w2.z; acc[11]+=yc*w2.w;
    acc[12]+=yc*w3.x; acc[13]+=yc*w3.y; acc[14]+=yc*w3.z; acc[15]+=yc*w3.w;
}

__global__ __launch_bounds__(256) void k_pb_g1(
    const float* __restrict__ pair, const float* __restrict__ wpc,
    const float* __restrict__ csb, const float* __restrict__ mask,
    u16* __restrict__ pb,
    const u16* __restrict__ shi, const u16* __restrict__ slo,
    const u16* __restrict__ gwh, const u16* __restrict__ gwl,
    const u16* __restrict__ skh, const u16* __restrict__ skl,
    const float* __restrict__ gate_b, const float* __restrict__ a_ln,
    u16* __restrict__ ahi, u16* __restrict__ alo)
{
    __shared__ u16 lA[2][128][40];
    __shared__ u16 lB[2][2][64][40];
    int bid = blockIdx.x, t = threadIdx.x;
    if (bid < 4096){
        // ---- pair_bias ----
        int row = bid*256 + t;
        int j = row & (NN-1);
        const float4* x4 = (const float4*)(pair + (size_t)row*CPAIR);
        float s=0.f, sq=0.f;
        float acc[16];
        #pragma unroll
        for (int h=0;h<16;h++) acc[h]=0.f;
        #pragma unroll 4
        for (int i=0;i<32;i++){
            float4 v = x4[i];
            s  += v.x+v.y+v.z+v.w;
            sq += v.x*v.x+v.y*v.y+v.z*v.z+v.w*v.w;
            fma16(v.x, wpc + (4*i+0)*16, acc);
            fma16(v.y, wpc + (4*i+1)*16, acc);
            fma16(v.z, wpc + (4*i+2)*16, acc);
            fma16(v.w, wpc + (4*i+3)*16, acc);
        }
        float mu = s*(1.f/128.f);
        float rs = rsqrtf(fmaxf(sq*(1.f/128.f)-mu*mu,0.f)+1e-5f);
        float mb = 1e8f*(mask[j]-1.f);
        #pragma unroll
        for (int h=0;h<16;h++){
            float outv = (acc[h]-mu*csb[h])*rs + csb[16+h] + mb;
            pb[((size_t)h<<20) + row] = f2bf(outv);
        }
        return;
    }
    // ---- G1: a = sigm(s@gate_w + gate_b)*a_ln + s@skip_w -> a planes ----
    int b = bid - 4096;
    int m0 = (b&15)*128, n0 = (b>>4)*64;
    int lane = t&63, w = t>>6;
    int fr = lane&15, fg = lane>>4;
    f32x4 acc[2][2][4];
    #pragma unroll
    for (int i=0;i<2;i++)
        #pragma unroll
        for (int mf=0;mf<2;mf++)
            #pragma unroll
            for (int nf=0;nf<4;nf++) acc[i][mf][nf] = (f32x4){0.f,0.f,0.f,0.f};
    gemm_tile<2>(shi, slo, gwh, gwl, skh, skl, m0, n0, t, lA, lB, acc);
    #pragma unroll
    for (int mf=0;mf<2;mf++){
        #pragma unroll
        for (int nf=0;nf<4;nf++){
            #pragma unroll
            for (int r=0;r<4;r++){
                int row = m0 + w*32 + mf*16 + fg*4 + r;
                int col = n0 + nf*16 + fr;
                size_t idx = (size_t)row*DIMM + col;
                float c0 = acc[0][mf][nf][r];
                float c1 = acc[1][mf][nf][r];
                float v = sigm(c0 + gate_b[col]) * a_ln[idx] + c1;
                u16 h,l; bfsplit(v,h,l); ahi[idx]=h; alo[idx]=l;
            }
        }
    }
}

// ---------------------------------------------------------------------------
// bf16x2-split MFMA GEMM (EPI 3/4 paths) — R10 structure
// ---------------------------------------------------------------------------
template<int EPI>
__global__ __launch_bounds__(256) void k_gemm(
    const u16* __restrict__ Ahp, const u16* __restrict__ Alp,
    const u16* __restrict__ B0h, const u16* __restrict__ B0l,
    const float* __restrict__ e0,
    float* __restrict__ o0,
    u16* __restrict__ oh, u16* __restrict__ ol)
{
    __shared__ u16 lA[2][128][40];
    __shared__ u16 lB[1][2][64][40];
    int m0 = blockIdx.x*128, n0 = blockIdx.y*64;
    int t = threadIdx.x, lane = t&63, w = t>>6;
    int fr = lane&15, fg = lane>>4;
    f32x4 acc[1][2][4];
    #pragma unroll
    for (int mf=0;mf<2;mf++)
        #pragma unroll
        for (int nf=0;nf<4;nf++) acc[0][mf][nf] = (f32x4){0.f,0.f,0.f,0.f};

    gemm_tile<1>(Ahp, Alp, B0h, B0l, nullptr, nullptr, m0, n0, t, lA, lB, acc);

    #pragma unroll
    for (int mf=0;mf<2;mf++){
        #pragma unroll
        for (int nf=0;nf<4;nf++){
            #pragma unroll
            for (int r=0;r<4;r++){
                int row = m0 + w*32 + mf*16 + fg*4 + r;
                int col = n0 + nf*16 + fr;
                size_t idx = (size_t)row*DIMM + col;
                float c0 = acc[0][mf][nf][r];
                if (EPI==3){           // o2 = c0 + bo -> split planes
                    float v = c0 + e0[col];
                    u16 h,l; bfsplit(v,h,l); oh[idx]=h; ol[idx]=l;
                } else {               // EPI==4: out = sigm(c0 + b_out) * o2
                    float o2v = bf2f(Ahp[idx]) + bf2f(Alp[idx]);
                    o0[idx] = sigm(c0 + e0[col]) * o2v;
                }
            }
        }
    }
}

// ---------------------------------------------------------------------------
// merged q/k (z=0) + v/gate (z=1) GEMM — R10 body, grid-level merge only
// ---------------------------------------------------------------------------
__global__ __launch_bounds__(256) void k_gemm_qkvg(
    const u16* __restrict__ Ahp, const u16* __restrict__ Alp,
    const u16* __restrict__ wqh, const u16* __restrict__ wql,
    const u16* __restrict__ wkh, const u16* __restrict__ wkl,
    const u16* __restrict__ wvh, const u16* __restrict__ wvl,
    const u16* __restrict__ wgh, const u16* __restrict__ wgl,
    const float* __restrict__ bgate,
    u16* __restrict__ qah, u16* __restrict__ qal,
    u16* __restrict__ kah, u16* __restrict__ kal,
    u16* __restrict__ vth, u16* __restrict__ vtl,
    float* __restrict__ g)
{
    __shared__ u16 lA[2][128][40];
    __shared__ u16 lB[2][2][64][40];
    int m0 = blockIdx.x*128, n0 = blockIdx.y*64;
    int z = blockIdx.z;
    const u16* B0h = z ? wvh : wqh;
    const u16* B0l = z ? wvl : wql;
    const u16* B1h = z ? wgh : wkh;
    const u16* B1l = z ? wgl : wkl;
    int t = threadIdx.x, lane = t&63, w = t>>6;
    int fr = lane&15, fg = lane>>4;
    f32x4 acc[2][2][4];
    #pragma unroll
    for (int i=0;i<2;i++)
        #pragma unroll
        for (int mf=0;mf<2;mf++)
            #pragma unroll
            for (int nf=0;nf<4;nf++) acc[i][mf][nf] = (f32x4){0.f,0.f,0.f,0.f};

    gemm_tile<2>(Ahp, Alp, B0h, B0l, B1h, B1l, m0, n0, t, lA, lB, acc);

    #pragma unroll
    for (int mf=0;mf<2;mf++){
        #pragma unroll
        for (int nf=0;nf<4;nf++){
            #pragma unroll
            for (int r=0;r<4;r++){
                int row = m0 + w*32 + mf*16 + fg*4 + r;
                int col = n0 + nf*16 + fr;
                size_t idx = (size_t)row*DIMM + col;
                int s2 = row>>10, n = row&(NN-1);
                int hh2 = col/CH, cc = col-hh2*CH;   // 16-col frag never straddles a head
                float c0 = acc[0][mf][nf][r];
                float c1 = acc[1][mf][nf][r];
                if (z==0){
                    size_t pidx = ((size_t)(s2*HEADS+hh2)*NN + n)*CH + cc;
                    u16 hx,lx;
                    bfsplit(c0*0.14433756729740643f, hx,lx);
                    qah[pidx]=hx; qal[pidx]=lx;
                    bfsplit(c1,hx,lx);
                    kah[pidx]=hx; kal[pidx]=lx;
                } else {
                    size_t vidx = ((size_t)(s2*HEADS+hh2)*CH + cc)*NN + n;
                    u16 hx,lx; bfsplit(c0,hx,lx);
                    vth[vidx]=hx; vtl[vidx]=lx;
                    g[idx] = sigm(c1 + bgate[col]);
                }
            }
        }
    }
}

// ---------------------------------------------------------------------------
// flash attention on MFMA (R12 verified form)
// ---------------------------------------------------------------------------
__global__ __launch_bounds__(256) void k_attn(
    const u16* __restrict__ qah, const u16* __restrict__ qal,
    const u16* __restrict__ kah, const u16* __restrict__ kal,
    const u16* __restrict__ vth, const u16* __restrict__ vtl,
    const u16* __restrict__ pb, const float* __restrict__ g,
    u16* __restrict__ oghi, u16* __restrict__ oglo)
{
    __shared__ u16 lQh[64][72], lQl[64][72], lKh[64][72], lKl[64][72];
    __shared__ u16 lVh[48][72], lVl[48][72];
    __shared__ u16 lP[4][16][72];
    int t = threadIdx.x, lane = t&63, w = t>>6;
    int fr = lane&15, fg = lane>>4;
    int m0 = blockIdx.x*64;
    int sh = blockIdx.y, s = sh>>4, h = sh&15;
    size_t qkbase = (size_t)sh*NN*CH;   // [s][h][n][48]
    size_t vbase  = (size_t)sh*CH*NN;   // [s][h][c][n]

    {
        int row = t>>2, which = t&3;
        u16* dst = (which==0)? &lQh[row][48] : (which==1)? &lQl[row][48] :
                   (which==2)? &lKh[row][48] : &lKl[row][48];
        *(int4*)dst     = make_int4(0,0,0,0);
        *(int4*)(dst+8) = make_int4(0,0,0,0);
    }
    {
        const u16* src0 = qah + qkbase + (size_t)m0*CH;
        const u16* src1 = qal + qkbase + (size_t)m0*CH;
        #pragma unroll
        for (int it=0; it<3; it++){
            int sid = t + it*256;
            int plane = sid>=384; int s2 = plane ? sid-384 : sid;
            int row = s2/6, seg = s2-row*6;
            int4 v = *(const int4*)((plane?src1:src0) + row*CH + seg*8);
            u16 (*dq)[72] = plane? lQl : lQh;
            *(int4*)(&dq[row][seg*8]) = v;
        }
    }
    __syncthreads();
    short8 aqh0 = *(const short8*)(&lQh[w*16+fr][fg*8]);
    short8 aqh1 = *(const short8*)(&lQh[w*16+fr][32+fg*8]);
    short8 aql0 = *(const short8*)(&lQl[w*16+fr][fg*8]);
    short8 aql1 = *(const short8*)(&lQl[w*16+fr][32+fg*8]);

    f32x4 acc_o[3];
    #pragma unroll
    for (int i=0;i<3;i++) acc_o[i]=(f32x4){0.f,0.f,0.f,0.f};
    float m[4], l[4];
    #pragma unroll
    for (int r=0;r<4;r++){ m[r]=-3e38f; l[r]=0.f; }
    int qrow_base = m0 + w*16 + fg*4;
    const u16* pbq = pb + ((size_t)h<<20) + (size_t)qrow_base*NN + fr;

    for (int kt=0; kt<16; kt++){
        int k0 = kt*64;
        int4 kreg[3], vreg[3];
        const u16* ksrc0 = kah + qkbase + (size_t)k0*CH;
        const u16* ksrc1 = kal + qkbase + (size_t)k0*CH;
        const u16* vsrc0 = vth + vbase + k0;
        const u16* vsrc1 = vtl + vbase + k0;
        #pragma unroll
        for (int it=0; it<3; it++){
            int sid = t + it*256;
            int plane = sid>=384; int s2 = plane ? sid-384 : sid;
            int row = s2/6, seg = s2-row*6;
            kreg[it] = *(const int4*)((plane?ksrc1:ksrc0) + row*CH + seg*8);
            int rowv = s2>>3, segv = s2&7;
            vreg[it] = *(const int4*)((plane?vsrc1:vsrc0) + (size_t)rowv*NN + segv*8);
        }
        u16 pbv[4][4];
        #pragma unroll
        for (int r=0;r<4;r++)
            #pragma unroll
            for (int nf=0;nf<4;nf++)
                pbv[r][nf] = pbq[(size_t)r*NN + k0 + nf*16];
        __syncthreads();
        #pragma unroll
        for (int it=0; it<3; it++){
            int sid = t + it*256;
            int plane = sid>=384; int s2 = plane ? sid-384 : sid;
            int row = s2/6, seg = s2-row*6;
            u16 (*dk)[72] = plane? lKl : lKh;
            *(int4*)(&dk[row][seg*8]) = kreg[it];
            int rowv = s2>>3, segv = s2&7;
            u16 (*dv)[72] = plane? lVl : lVh;
            *(int4*)(&dv[rowv][segv*8]) = vreg[it];
        }
        __syncthreads();
        f32x4 sc[4];
        #pragma unroll
        for (int nf=0;nf<4;nf++){
            short8 bh0 = *(const short8*)(&lKh[nf*16+fr][fg*8]);
            short8 bh1 = *(const short8*)(&lKh[nf*16+fr][32+fg*8]);
            short8 bl0 = *(const short8*)(&lKl[nf*16+fr][fg*8]);
            short8 bl1 = *(const short8*)(&lKl[nf*16+fr][32+fg*8]);
            f32x4 a = (f32x4){0.f,0.f,0.f,0.f};
            a = __builtin_amdgcn_mfma_f32_16x16x32_bf16(aqh0, bh0, a, 0,0,0);
            a = __builtin_amdgcn_mfma_f32_16x16x32_bf16(aqh1, bh1, a, 0,0,0);
            a = __builtin_amdgcn_mfma_f32_16x16x32_bf16(aqh0, bl0, a, 0,0,0);
            a = __builtin_amdgcn_mfma_f32_16x16x32_bf16(aqh1, bl1, a, 0,0,0);
            a = __builtin_amdgcn_mfma_f32_16x16x32_bf16(aql0, bh0, a, 0,0,0);
            a = __builtin_amdgcn_mfma_f32_16x16x32_bf16(aql1, bh1, a, 0,0,0);
            sc[nf]=a;
        }
        float mn[4];
        #pragma unroll
        for (int r=0;r<4;r++){
            float v0 = sc[0][r]+bf2f(pbv[r][0]);
            float v1 = sc[1][r]+bf2f(pbv[r][1]);
            float v2 = sc[2][r]+bf2f(pbv[r][2]);
            float v3 = sc[3][r]+bf2f(pbv[r][3]);
            sc[0][r]=v0; sc[1][r]=v1; sc[2][r]=v2; sc[3][r]=v3;
            float mx = fmaxf(fmaxf(v0,v1),fmaxf(v2,v3));
            mx = fmaxf(mx, __shfl_xor(mx,1,64));
            mx = fmaxf(mx, __shfl_xor(mx,2,64));
            mx = fmaxf(mx, __shfl_xor(mx,4,64));
            mx = fmaxf(mx, __shfl_xor(mx,8,64));
            mn[r]=mx;
        }
        #pragma unroll
        for (int r=0;r<4;r++){
            float mnew = fmaxf(m[r], mn[r]);
            float corr = __expf(m[r]-mnew);
            m[r]=mnew;
            float ps=0.f;
            #pragma unroll
            for (int nf=0;nf<4;nf++){
                float p = __expf(sc[nf][r]-mnew);
                u16 pu = f2bf(p);
                ps += bf2f(pu);
                lP[w][fg*4+r][nf*16+fr] = pu;
            }
            l[r] = l[r]*corr + ps;
            acc_o[0][r]*=corr; acc_o[1][r]*=corr; acc_o[2][r]*=corr;
        }
        short8 pa0 = *(const short8*)(&lP[w][fr][fg*8]);
        short8 pa1 = *(const short8*)(&lP[w][fr][32+fg*8]);
        #pragma unroll
        for (int cf=0;cf<3;cf++){
            short8 vh0 = *(const short8*)(&lVh[cf*16+fr][fg*8]);
            short8 vh1 = *(const short8*)(&lVh[cf*16+fr][32+fg*8]);
            short8 vl0 = *(const short8*)(&lVl[cf*16+fr][fg*8]);
            short8 vl1 = *(const short8*)(&lVl[cf*16+fr][32+fg*8]);
            acc_o[cf] = __builtin_amdgcn_mfma_f32_16x16x32_bf16(pa0, vh0, acc_o[cf], 0,0,0);
            acc_o[cf] = __builtin_amdgcn_mfma_f32_16x16x32_bf16(pa1, vh1, acc_o[cf], 0,0,0);
            acc_o[cf] = __builtin_amdgcn_mfma_f32_16x16x32_bf16(pa0, vl0, acc_o[cf], 0,0,0);
            acc_o[cf] = __builtin_amdgcn_mfma_f32_16x16x32_bf16(pa1, vl1, acc_o[cf], 0,0,0);
        }
    }
    float rl[4];
    #pragma unroll
    for (int r=0;r<4;r++){
        float lv = l[r];
        lv += __shfl_xor(lv,1,64);
        lv += __shfl_xor(lv,2,64);
        lv += __shfl_xor(lv,4,64);
        lv += __shfl_xor(lv,8,64);
        rl[r] = 1.f/lv;
    }
    #pragma unroll
    for (int cf=0;cf<3;cf++){
        #pragma unroll
        for (int r=0;r<4;r++){
            size_t orow = ((size_t)(s*NN + m0 + w*16 + fg*4 + r))*DIMM + h*CH + cf*16 + fr;
            float val = acc_o[cf][r]*rl[r] * g[orow];
            u16 hh,ll; bfsplit(val,hh,ll);
            oghi[orow]=hh; oglo[orow]=ll;
        }
    }
}

// ---------------------------------------------------------------------------
extern "C" void kernel_launch(void* const* d_in, const int* in_sizes, int n_in,
                              void* d_out, int out_size, void* d_ws, size_t ws_size,
                              hipStream_t stream)
{
    const float* srep   = (const float*)d_in[0];
    const float* sproj  = (const float*)d_in[1];
    const float* pair   = (const float*)d_in[2];
    const float* mask   = (const float*)d_in[3];
    const float* s_w    = (const float*)d_in[4];
    const float* gate_w = (const float*)d_in[5];
    const float* gate_b = (const float*)d_in[6];
    const float* skip_w = (const float*)d_in[7];
    const float* wq     = (const float*)d_in[8];
    const float* wk     = (const float*)d_in[9];
    const float* wv     = (const float*)d_in[10];
    const float* w_gate = (const float*)d_in[11];
    const float* b_gate = (const float*)d_in[12];
    const float* wo     = (const float*)d_in[13];
    const float* bo     = (const float*)d_in[14];
    const float* plnw   = (const float*)d_in[15];
    const float* plnb   = (const float*)d_in[16];
    const float* w_pair = (const float*)d_in[17];
    const float* w_out  = (const float*)d_in[18];
    const float* b_out  = (const float*)d_in[19];
    float* out = (float*)d_out;

    const size_t T  = (size_t)NROWS*DIMM;       // 1,572,864
    const size_t W  = (size_t)DIMM*DIMM;        // 589,824
    const size_t PB = (size_t)HEADS*NN*NN;      // 16,777,216

    char* p = (char*)d_ws;
    float* a_ln = (float*)p; p += T*4;
    float* g    = (float*)p; p += T*4;
    float* wpc  = (float*)p; p += 2048*4;
    float* csb  = (float*)p; p += 32*4;
    u16* shi  = (u16*)p; p += T*2;
    u16* slo  = (u16*)p; p += T*2;
    u16* ahi  = (u16*)p; p += T*2;
    u16* alo  = (u16*)p; p += T*2;
    u16* oghi = (u16*)p; p += T*2;
    u16* oglo = (u16*)p; p += T*2;
    u16* o2hi = (u16*)p; p += T*2;
    u16* o2lo = (u16*)p; p += T*2;
    u16* qah  = (u16*)p; p += T*2;
    u16* qal  = (u16*)p; p += T*2;
    u16* kah  = (u16*)p; p += T*2;
    u16* kal  = (u16*)p; p += T*2;
    u16* vth  = (u16*)p; p += T*2;
    u16* vtl  = (u16*)p; p += T*2;
    u16* pbias= (u16*)p; p += PB*2;
    u16* wt   = (u16*)p; p += 16*W*2;

    #define WH(i) (wt + (size_t)(i)*2*W)
    #define WL(i) (wt + (size_t)(i)*2*W + W)

    // K1: fused ln_single + wsplit + pair_pre (all independent)
    k_pre<<<2048+1152+1, 256, 0, stream>>>(
        srep, sproj, s_w, a_ln, shi, slo,
        gate_w, skip_w, wq, wk, wv, w_gate, wo, w_out, wt,
        plnw, plnb, w_pair, wpc, csb);

    // K2: fused pair_bias + G1 (independent; HBM-bound || MFMA-bound)
    k_pb_g1<<<4096+192, 256, 0, stream>>>(
        pair, wpc, csb, mask, pbias,
        shi, slo, WH(0), WL(0), WH(1), WL(1), gate_b, a_ln, ahi, alo);

    // K3: merged q/k + v/gate
    k_gemm_qkvg<<<dim3(NROWS/128, DIMM/64, 2), 256, 0, stream>>>(
        ahi, alo, WH(2), WL(2), WH(3), WL(3), WH(4), WL(4), WH(5), WL(5),
        b_gate, qah, qal, kah, kal, vth, vtl, g);

    // K4: attention
    k_attn<<<dim3(NN/64, 2*HEADS), 256, 0, stream>>>(
        qah, qal, kah, kal, vth, vtl, pbias, g, oghi, oglo);

    dim3 gg(NROWS/128, DIMM/64);
    // K5: o2 = og@wo + bo
    k_gemm<3><<<gg, 256, 0, stream>>>(oghi, oglo, WH(6), WL(6), bo,
                                      nullptr, o2hi, o2lo);
    // K6: out = sigm(o2@w_out + b_out) * o2
    k_gemm<4><<<gg, 256, 0, stream>>>(o2hi, o2lo, WH(7), WL(7), b_out,
                                      out, nullptr, nullptr);
    #undef WH
    #undef WL
}